// Round 1
// baseline (712.308 us; speedup 1.0000x reference)
//
#include <hip/hip_runtime.h>

#define Bsz 8192
#define Lctx 64
#define Ddim 512
#define DK 64
#define Ttag 128

__device__ __forceinline__ float wave_sum(float v) {
#pragma unroll
    for (int m = 32; m > 0; m >>= 1) v += __shfl_xor(v, m, 64);
    return v;
}

__device__ __forceinline__ float dot4(float4 a, float4 b) {
    return a.x * b.x + a.y * b.y + a.z * b.z + a.w * b.w;
}

__device__ __forceinline__ unsigned short f2bf(float f) {
    unsigned int u = __float_as_uint(f);
    u = u + 0x7fffu + ((u >> 16) & 1u);   // round-to-nearest-even
    return (unsigned short)(u >> 16);
}
__device__ __forceinline__ float bflo(unsigned int v) { return __uint_as_float(v << 16); }
__device__ __forceinline__ float bfhi(unsigned int v) { return __uint_as_float(v & 0xffff0000u); }

// ---------------------------------------------------------------------------
// q̃[b] = W_K^T (W_Q c[b]).  One wave handles 8 batch rows; W_Q/W_K streamed
// from L2 (128 KB each, hot).  Grid 256 x 256 threads covers all 8192 rows.
// ---------------------------------------------------------------------------
__global__ __launch_bounds__(256) void k_qtilde(
    const float* __restrict__ C, const float* __restrict__ WQ,
    const float* __restrict__ WK, float* __restrict__ qt)
{
    const int lane = threadIdx.x & 63;
    const int gw = blockIdx.x * 4 + (threadIdx.x >> 6);
    const int b0 = gw * 8;

    float4 c0[8], c1[8];
#pragma unroll
    for (int r = 0; r < 8; ++r) {
        const float4* row = (const float4*)(C + (size_t)(b0 + r) * Ddim);
        c0[r] = row[lane];
        c1[r] = row[64 + lane];
    }
    // phase 1: t[b,k] = c[b] . W_Q[k]   (lane j ends up holding t[b_r, j])
    float tv[8];
#pragma unroll
    for (int r = 0; r < 8; ++r) tv[r] = 0.f;
    for (int k = 0; k < DK; ++k) {
        const float4* wrow = (const float4*)(WQ + (size_t)k * Ddim);
        const float4 w0 = wrow[lane];
        const float4 w1 = wrow[64 + lane];
#pragma unroll
        for (int r = 0; r < 8; ++r) {
            float p = dot4(c0[r], w0) + dot4(c1[r], w1);
            p = wave_sum(p);
            if (lane == k) tv[r] = p;
        }
    }
    // phase 2: q̃[b] = sum_k t[b,k] * W_K[k,:]
    float4 a0[8], a1[8];
#pragma unroll
    for (int r = 0; r < 8; ++r) {
        a0[r] = make_float4(0.f, 0.f, 0.f, 0.f);
        a1[r] = make_float4(0.f, 0.f, 0.f, 0.f);
    }
    for (int k = 0; k < DK; ++k) {
        const float4* wrow = (const float4*)(WK + (size_t)k * Ddim);
        const float4 w0 = wrow[lane];
        const float4 w1 = wrow[64 + lane];
#pragma unroll
        for (int r = 0; r < 8; ++r) {
            const float tk = __shfl(tv[r], k, 64);
            a0[r].x += tk * w0.x; a0[r].y += tk * w0.y;
            a0[r].z += tk * w0.z; a0[r].w += tk * w0.w;
            a1[r].x += tk * w1.x; a1[r].y += tk * w1.y;
            a1[r].z += tk * w1.z; a1[r].w += tk * w1.w;
        }
    }
#pragma unroll
    for (int r = 0; r < 8; ++r) {
        float4* orow = (float4*)(qt + (size_t)(b0 + r) * Ddim);
        orow[lane] = a0[r];
        orow[64 + lane] = a1[r];
    }
}

// ---------------------------------------------------------------------------
// Ragged attention, one block per batch row.  Single global pass over x[b]:
// scores computed while staging rows into LDS as bf16 (64 KB -> 2 blocks/CU).
// Also writes the mdesc / cand slices of deep_in (free concat).
// ---------------------------------------------------------------------------
__global__ __launch_bounds__(256) void k_attn(
    const float* __restrict__ X, const float* __restrict__ qt,
    const int* __restrict__ clen, const float* __restrict__ mdesc,
    const float* __restrict__ cand, float* __restrict__ din)
{
    __shared__ unsigned short xl[Lctx][Ddim];   // 64 KB bf16 staging
    __shared__ float qtl[Ddim];
    __shared__ float sl[Lctx];
    __shared__ float pl[Lctx];

    const int b = blockIdx.x;
    const int tid = threadIdx.x;
    const int wave = tid >> 6, lane = tid & 63;

    if (tid < 128)
        ((float4*)qtl)[tid] = ((const float4*)(qt + (size_t)b * Ddim))[tid];
    __syncthreads();

    const float4 q0 = ((const float4*)qtl)[lane];
    const float4 q1 = ((const float4*)qtl)[64 + lane];
    const float4* xb = (const float4*)(X + (size_t)b * Lctx * Ddim);

    // phase A: wave w handles rows w*16 .. w*16+15; score + bf16 stage
    for (int i = 0; i < 16; ++i) {
        const int l = wave * 16 + i;
        const float4 x0 = xb[l * 128 + lane];
        const float4 x1 = xb[l * 128 + 64 + lane];
        float p = dot4(x0, q0) + dot4(x1, q1);
        uint2 pk0, pk1;
        pk0.x = (unsigned)f2bf(x0.x) | ((unsigned)f2bf(x0.y) << 16);
        pk0.y = (unsigned)f2bf(x0.z) | ((unsigned)f2bf(x0.w) << 16);
        pk1.x = (unsigned)f2bf(x1.x) | ((unsigned)f2bf(x1.y) << 16);
        pk1.y = (unsigned)f2bf(x1.z) | ((unsigned)f2bf(x1.w) << 16);
        *(uint2*)&xl[l][lane * 4] = pk0;
        *(uint2*)&xl[l][256 + lane * 4] = pk1;
        p = wave_sum(p);
        if (lane == 0) sl[l] = p;
    }
    __syncthreads();

    // masked softmax (redundant per-thread scan; len==0 -> all-zero probs)
    const int len = clen[b];
    float m = -1e30f;
    for (int l = 0; l < len; ++l) m = fmaxf(m, sl[l]);
    float denom = 0.f;
    for (int l = 0; l < len; ++l) denom += __expf(sl[l] - m);
    const float rden = 1.f / fmaxf(denom, 1e-30f);
    if (tid < Lctx) pl[tid] = (tid < len) ? __expf(sl[tid] - m) * rden : 0.f;
    __syncthreads();

    // phase B: api_context[d] = sum_l p[l] * x[l,d], each thread owns 2 d's
    const int d0 = tid * 2;
    float2 acc = make_float2(0.f, 0.f);
    for (int l = 0; l < len; ++l) {
        const float p = pl[l];
        const unsigned v = *(const unsigned*)&xl[l][d0];
        acc.x += p * bflo(v);
        acc.y += p * bfhi(v);
    }
    float* dr = din + (size_t)b * 1536;
    *(float2*)(dr + 512 + d0) = acc;

    // concat: din[:,0:512)=mdesc, din[:,1024:1536)=cand
    if (tid < 128)
        ((float4*)dr)[tid] = ((const float4*)(mdesc + (size_t)b * Ddim))[tid];
    else
        ((float4*)dr)[256 + (tid - 128)] =
            ((const float4*)(cand + (size_t)b * Ddim))[tid - 128];
}

// ---------------------------------------------------------------------------
// Wide branch: one block per row, 16640-elem dot.  wide_w stays L2-hot.
// ---------------------------------------------------------------------------
__global__ __launch_bounds__(256) void k_wide(
    const float* __restrict__ mt, const float* __restrict__ tt,
    const float* __restrict__ cp, const float* __restrict__ ww,
    const float* __restrict__ wb, float* __restrict__ wl)
{
    const int b = blockIdx.x;
    const int tid = threadIdx.x;
    const int wave = tid >> 6, lane = tid & 63;
    float acc = 0.f;
    if (tid < 64) {   // the two 128-wide tag blocks
        float4 v;
        if (tid < 32) v = ((const float4*)(mt + (size_t)b * Ttag))[tid];
        else          v = ((const float4*)(tt + (size_t)b * Ttag))[tid - 32];
        const float4 w = ((const float4*)ww)[tid];
        acc += dot4(v, w);
    }
    const float4* cp4 = (const float4*)(cp + (size_t)b * (Ttag * Ttag));
    const float4* ww4 = (const float4*)(ww + 2 * Ttag);
#pragma unroll 4
    for (int i = tid; i < (Ttag * Ttag) / 4; i += 256)
        acc += dot4(cp4[i], ww4[i]);
    acc = wave_sum(acc);
    __shared__ float red[4];
    if (lane == 0) red[wave] = acc;
    __syncthreads();
    if (tid == 0) wl[b] = red[0] + red[1] + red[2] + red[3] + wb[0];
}

// ---------------------------------------------------------------------------
// fp32 tiled GEMM: C[M,N] = relu(A[M,K] @ W[N,K]^T + bias).
// BM = TM*16, BN=128, BK=16; 256 threads, micro-tile TM x 8.
// Prefetch-to-regs hides the staging latency across the barrier.
// ---------------------------------------------------------------------------
template <int TM>
__global__ __launch_bounds__(256) void k_gemm_relu(
    const float* __restrict__ A, const float* __restrict__ W,
    const float* __restrict__ bias, float* __restrict__ Cout,
    const int K, const int N, const int relu)
{
    constexpr int BM = TM * 16;
    constexpr int BK = 16;
    constexpr int BN = 128;
    constexpr int NA = (BM * 4 + 255) / 256;   // float4 loads per thread for A
    __shared__ float As[BK][BM + 4];
    __shared__ float Bs[BK][BN + 4];
    const int tid = threadIdx.x;
    const int tx = tid & 15, ty = tid >> 4;
    const size_t m0 = (size_t)blockIdx.x * BM;
    const size_t n0 = (size_t)blockIdx.y * BN;

    float acc[TM][8];
#pragma unroll
    for (int i = 0; i < TM; ++i)
#pragma unroll
        for (int j = 0; j < 8; ++j) acc[i][j] = 0.f;

    float4 arg[NA], brg[2];
    auto loadA = [&](int k0) {
#pragma unroll
        for (int n = 0; n < NA; ++n) {
            const int i = tid + n * 256;
            if (BM * 4 >= 256 || i < BM * 4) {
                const int row = i >> 2, kc = (i & 3) << 2;
                arg[n] = *(const float4*)(A + (m0 + row) * K + k0 + kc);
            }
        }
    };
    auto loadB = [&](int k0) {
#pragma unroll
        for (int n = 0; n < 2; ++n) {
            const int i = tid + n * 256;
            const int row = i >> 2, kc = (i & 3) << 2;
            brg[n] = *(const float4*)(W + (n0 + row) * K + k0 + kc);
        }
    };

    loadA(0);
    loadB(0);
    for (int k0 = 0; k0 < K; k0 += BK) {
        __syncthreads();
#pragma unroll
        for (int n = 0; n < NA; ++n) {
            const int i = tid + n * 256;
            if (BM * 4 >= 256 || i < BM * 4) {
                const int row = i >> 2, kc = (i & 3) << 2;
                As[kc + 0][row] = arg[n].x;
                As[kc + 1][row] = arg[n].y;
                As[kc + 2][row] = arg[n].z;
                As[kc + 3][row] = arg[n].w;
            }
        }
#pragma unroll
        for (int n = 0; n < 2; ++n) {
            const int i = tid + n * 256;
            const int row = i >> 2, kc = (i & 3) << 2;
            Bs[kc + 0][row] = brg[n].x;
            Bs[kc + 1][row] = brg[n].y;
            Bs[kc + 2][row] = brg[n].z;
            Bs[kc + 3][row] = brg[n].w;
        }
        __syncthreads();
        if (k0 + BK < K) { loadA(k0 + BK); loadB(k0 + BK); }
#pragma unroll
        for (int k = 0; k < BK; ++k) {
            float a[TM];
            if constexpr (TM == 8) {
                const float4 a0 = *(const float4*)&As[k][ty * 8];
                const float4 a1 = *(const float4*)&As[k][ty * 8 + 4];
                a[0] = a0.x; a[1] = a0.y; a[2] = a0.z; a[3] = a0.w;
                a[4] = a1.x; a[5] = a1.y; a[6] = a1.z; a[7] = a1.w;
            } else if constexpr (TM == 4) {
                const float4 a0 = *(const float4*)&As[k][ty * 4];
                a[0] = a0.x; a[1] = a0.y; a[2] = a0.z; a[3] = a0.w;
            } else {
                const float2 a0 = *(const float2*)&As[k][ty * 2];
                a[0] = a0.x; a[1] = a0.y;
            }
            const float4 b0 = *(const float4*)&Bs[k][tx * 8];
            const float4 b1 = *(const float4*)&Bs[k][tx * 8 + 4];
            const float bcol[8] = {b0.x, b0.y, b0.z, b0.w, b1.x, b1.y, b1.z, b1.w};
#pragma unroll
            for (int i = 0; i < TM; ++i)
#pragma unroll
                for (int j = 0; j < 8; ++j)
                    acc[i][j] = fmaf(a[i], bcol[j], acc[i][j]);
        }
    }
    float bb[8];
#pragma unroll
    for (int j = 0; j < 8; ++j) bb[j] = bias[n0 + tx * 8 + j];
#pragma unroll
    for (int i = 0; i < TM; ++i) {
        const size_t r = m0 + ty * TM + i;
        float o[8];
#pragma unroll
        for (int j = 0; j < 8; ++j) {
            o[j] = acc[i][j] + bb[j];
            if (relu) o[j] = fmaxf(o[j], 0.f);
        }
        *(float4*)(Cout + r * N + n0 + tx * 8) = make_float4(o[0], o[1], o[2], o[3]);
        *(float4*)(Cout + r * N + n0 + tx * 8 + 4) = make_float4(o[4], o[5], o[6], o[7]);
    }
}

// ---------------------------------------------------------------------------
// Final: deep_out = h3 . d4w + d4b; out = sigmoid(ww*sigmoid(wide) + dw*deep + bias)
// ---------------------------------------------------------------------------
__global__ __launch_bounds__(256) void k_final(
    const float* __restrict__ h3, const float* __restrict__ d4w,
    const float* __restrict__ d4b, const float* __restrict__ wl,
    const float* __restrict__ wwt, const float* __restrict__ dwt,
    const float* __restrict__ bs, float* __restrict__ out)
{
    const int lane = threadIdx.x & 63;
    const int b = blockIdx.x * 4 + (threadIdx.x >> 6);
    float v = h3[(size_t)b * 128 + lane] * d4w[lane]
            + h3[(size_t)b * 128 + 64 + lane] * d4w[64 + lane];
    v = wave_sum(v);
    if (lane == 0) {
        const float deep = v + d4b[0];
        const float wo = 1.f / (1.f + __expf(-wl[b]));
        const float z = wwt[0] * wo + dwt[0] * deep + bs[0];
        out[b] = 1.f / (1.f + __expf(-z));
    }
}

extern "C" void kernel_launch(void* const* d_in, const int* in_sizes, int n_in,
                              void* d_out, int out_size, void* d_ws, size_t ws_size,
                              hipStream_t stream)
{
    const float* mt    = (const float*)d_in[0];
    const float* tt    = (const float*)d_in[1];
    const float* cp    = (const float*)d_in[2];
    const float* X     = (const float*)d_in[3];
    const float* cand  = (const float*)d_in[4];
    const float* mdesc = (const float*)d_in[5];
    const int*   clen  = (const int*)d_in[6];
    const float* WK    = (const float*)d_in[7];
    const float* WQ    = (const float*)d_in[8];
    const float* ww    = (const float*)d_in[9];
    const float* wb    = (const float*)d_in[10];
    const float* d1w   = (const float*)d_in[11];
    const float* d1b   = (const float*)d_in[12];
    const float* d2w   = (const float*)d_in[13];
    const float* d2b   = (const float*)d_in[14];
    const float* d3w   = (const float*)d_in[15];
    const float* d3b   = (const float*)d_in[16];
    const float* d4w   = (const float*)d_in[17];
    const float* d4b   = (const float*)d_in[18];
    const float* wwt   = (const float*)d_in[19];
    const float* dwt   = (const float*)d_in[20];
    const float* bs    = (const float*)d_in[21];
    float* out = (float*)d_out;

    // workspace layout (floats): din[B*1536] | qt[B*512](=h1 alias) | h2[B*256]
    //                            | h3[B*128] | wl[B]      total ~76 MB
    float* wsf = (float*)d_ws;
    float* din = wsf;
    float* qt  = din + (size_t)Bsz * 1536;
    float* h1  = qt;   // qt dead after k_attn; gemm1 reuses the space
    float* h2  = h1 + (size_t)Bsz * 512;
    float* h3  = h2 + (size_t)Bsz * 256;
    float* wl  = h3 + (size_t)Bsz * 128;

    hipLaunchKernelGGL(k_qtilde, dim3(256), dim3(256), 0, stream, cand, WQ, WK, qt);
    hipLaunchKernelGGL(k_attn, dim3(Bsz), dim3(256), 0, stream,
                       X, qt, clen, mdesc, cand, din);
    hipLaunchKernelGGL(k_wide, dim3(Bsz), dim3(256), 0, stream,
                       mt, tt, cp, ww, wb, wl);
    hipLaunchKernelGGL((k_gemm_relu<8>), dim3(64, 4), dim3(256), 0, stream,
                       din, d1w, d1b, h1, 1536, 512, 1);
    hipLaunchKernelGGL((k_gemm_relu<4>), dim3(128, 2), dim3(256), 0, stream,
                       h1, d2w, d2b, h2, 512, 256, 1);
    hipLaunchKernelGGL((k_gemm_relu<2>), dim3(256, 1), dim3(256), 0, stream,
                       h2, d3w, d3b, h3, 256, 128, 1);
    hipLaunchKernelGGL(k_final, dim3(Bsz / 4), dim3(256), 0, stream,
                       h3, d4w, d4b, wl, wwt, dwt, bs, out);
}

// Round 2
// 596.058 us; speedup vs baseline: 1.1950x; 1.1950x over previous
//
#include <hip/hip_runtime.h>

#define Bsz 8192
#define Lctx 64
#define Ddim 512
#define DK 64
#define Ttag 128

using f32x4 = __attribute__((ext_vector_type(4))) float;
using bf16x8 = __attribute__((ext_vector_type(8))) short;

__device__ __forceinline__ float wave_sum(float v) {
#pragma unroll
    for (int m = 32; m > 0; m >>= 1) v += __shfl_xor(v, m, 64);
    return v;
}

__device__ __forceinline__ float dot4(float4 a, float4 b) {
    return a.x * b.x + a.y * b.y + a.z * b.z + a.w * b.w;
}

__device__ __forceinline__ unsigned f2bf(float f) {  // RNE, low 16 valid
    unsigned int u = __float_as_uint(f);
    u = u + 0x7fffu + ((u >> 16) & 1u);
    return u >> 16;
}
__device__ __forceinline__ unsigned pack2(float a, float b) {
    return f2bf(a) | (f2bf(b) << 16);
}
__device__ __forceinline__ float bflo(unsigned int v) { return __uint_as_float(v << 16); }
__device__ __forceinline__ float bfhi(unsigned int v) { return __uint_as_float(v & 0xffff0000u); }
__device__ __forceinline__ float bf2f(unsigned short u) { return __uint_as_float((unsigned)u << 16); }

// ---------------------------------------------------------------------------
// fp32 -> bf16 bulk convert (weights).  n4 = element count / 4.
// ---------------------------------------------------------------------------
__global__ __launch_bounds__(256) void k_f2bf(
    const float* __restrict__ s, unsigned short* __restrict__ d, int n4)
{
    const int i = blockIdx.x * 256 + threadIdx.x;
    if (i < n4) {
        const float4 v = ((const float4*)s)[i];
        uint2 w;
        w.x = pack2(v.x, v.y);
        w.y = pack2(v.z, v.w);
        *(uint2*)&d[(size_t)i * 4] = w;
    }
}

// ---------------------------------------------------------------------------
// q̃[b] = W_K^T (W_Q c[b]).  One wave handles 8 batch rows.
// ---------------------------------------------------------------------------
__global__ __launch_bounds__(256) void k_qtilde(
    const float* __restrict__ C, const float* __restrict__ WQ,
    const float* __restrict__ WK, float* __restrict__ qt)
{
    const int lane = threadIdx.x & 63;
    const int gw = blockIdx.x * 4 + (threadIdx.x >> 6);
    const int b0 = gw * 8;

    float4 c0[8], c1[8];
#pragma unroll
    for (int r = 0; r < 8; ++r) {
        const float4* row = (const float4*)(C + (size_t)(b0 + r) * Ddim);
        c0[r] = row[lane];
        c1[r] = row[64 + lane];
    }
    float tv[8];
#pragma unroll
    for (int r = 0; r < 8; ++r) tv[r] = 0.f;
    for (int k = 0; k < DK; ++k) {
        const float4* wrow = (const float4*)(WQ + (size_t)k * Ddim);
        const float4 w0 = wrow[lane];
        const float4 w1 = wrow[64 + lane];
#pragma unroll
        for (int r = 0; r < 8; ++r) {
            float p = dot4(c0[r], w0) + dot4(c1[r], w1);
            p = wave_sum(p);
            if (lane == k) tv[r] = p;
        }
    }
    float4 a0[8], a1[8];
#pragma unroll
    for (int r = 0; r < 8; ++r) {
        a0[r] = make_float4(0.f, 0.f, 0.f, 0.f);
        a1[r] = make_float4(0.f, 0.f, 0.f, 0.f);
    }
    for (int k = 0; k < DK; ++k) {
        const float4* wrow = (const float4*)(WK + (size_t)k * Ddim);
        const float4 w0 = wrow[lane];
        const float4 w1 = wrow[64 + lane];
#pragma unroll
        for (int r = 0; r < 8; ++r) {
            const float tk = __shfl(tv[r], k, 64);
            a0[r].x += tk * w0.x; a0[r].y += tk * w0.y;
            a0[r].z += tk * w0.z; a0[r].w += tk * w0.w;
            a1[r].x += tk * w1.x; a1[r].y += tk * w1.y;
            a1[r].z += tk * w1.z; a1[r].w += tk * w1.w;
        }
    }
#pragma unroll
    for (int r = 0; r < 8; ++r) {
        float4* orow = (float4*)(qt + (size_t)(b0 + r) * Ddim);
        orow[lane] = a0[r];
        orow[64 + lane] = a1[r];
    }
}

// ---------------------------------------------------------------------------
// Ragged attention, register-resident (no big LDS -> 4 blocks/CU).
// Wave w holds rows w*16..w*16+15 as packed bf16 in 64 VGPRs.
// Output din row written as bf16 (feeds MFMA GEMM).
// ---------------------------------------------------------------------------
__global__ __launch_bounds__(256, 4) void k_attn(
    const float* __restrict__ X, const float* __restrict__ qt,
    const int* __restrict__ clen, const float* __restrict__ mdesc,
    const float* __restrict__ cand, unsigned short* __restrict__ din)
{
    __shared__ float sl[Lctx];
    __shared__ float pl[Lctx];
    __shared__ float part[4][Ddim];   // 8 KB cross-wave partials

    const int b = blockIdx.x;
    const int tid = threadIdx.x;
    const int wave = tid >> 6, lane = tid & 63;

    const float4* qrow = (const float4*)(qt + (size_t)b * Ddim);
    const float4 q0 = qrow[lane];
    const float4 q1 = qrow[64 + lane];
    const float4* xb = (const float4*)(X + (size_t)b * Lctx * Ddim);

    uint2 pk[16][2];   // 16 rows x 8 bf16 per lane

#pragma unroll
    for (int c = 0; c < 8; ++c) {
        float4 t0[2], t1[2];
#pragma unroll
        for (int i = 0; i < 2; ++i) {
            const int l = wave * 16 + c * 2 + i;
            t0[i] = xb[l * 128 + lane];
            t1[i] = xb[l * 128 + 64 + lane];
        }
#pragma unroll
        for (int i = 0; i < 2; ++i) {
            const int r = c * 2 + i;
            float p = dot4(t0[i], q0) + dot4(t1[i], q1);
            pk[r][0].x = pack2(t0[i].x, t0[i].y);
            pk[r][0].y = pack2(t0[i].z, t0[i].w);
            pk[r][1].x = pack2(t1[i].x, t1[i].y);
            pk[r][1].y = pack2(t1[i].z, t1[i].w);
            p = wave_sum(p);
            if (lane == 0) sl[wave * 16 + r] = p;
        }
    }
    __syncthreads();

    const int len = clen[b];
    float m = -1e30f;
    for (int l = 0; l < len; ++l) m = fmaxf(m, sl[l]);
    float denom = 0.f;
    for (int l = 0; l < len; ++l) denom += __expf(sl[l] - m);
    const float rden = 1.f / fmaxf(denom, 1e-30f);
    if (tid < Lctx) pl[tid] = (tid < len) ? __expf(sl[tid] - m) * rden : 0.f;
    __syncthreads();

    float4 a0 = make_float4(0.f, 0.f, 0.f, 0.f);
    float4 a1 = make_float4(0.f, 0.f, 0.f, 0.f);
#pragma unroll
    for (int r = 0; r < 16; ++r) {
        const float p = pl[wave * 16 + r];
        a0.x += p * bflo(pk[r][0].x); a0.y += p * bfhi(pk[r][0].x);
        a0.z += p * bflo(pk[r][0].y); a0.w += p * bfhi(pk[r][0].y);
        a1.x += p * bflo(pk[r][1].x); a1.y += p * bfhi(pk[r][1].x);
        a1.z += p * bflo(pk[r][1].y); a1.w += p * bfhi(pk[r][1].y);
    }
    *(float4*)&part[wave][lane * 4] = a0;
    *(float4*)&part[wave][256 + lane * 4] = a1;
    __syncthreads();

    unsigned short* dr = din + (size_t)b * 1536;
    {
        const int d0 = tid * 2;
        const float2 s0 = *(const float2*)&part[0][d0];
        const float2 s1 = *(const float2*)&part[1][d0];
        const float2 s2 = *(const float2*)&part[2][d0];
        const float2 s3 = *(const float2*)&part[3][d0];
        const float vx = s0.x + s1.x + s2.x + s3.x;
        const float vy = s0.y + s1.y + s2.y + s3.y;
        *(unsigned*)&dr[512 + d0] = pack2(vx, vy);
    }
    {
        const float4 v = (tid < 128)
            ? ((const float4*)(mdesc + (size_t)b * Ddim))[tid]
            : ((const float4*)(cand + (size_t)b * Ddim))[tid - 128];
        uint2 w;
        w.x = pack2(v.x, v.y);
        w.y = pack2(v.z, v.w);
        const int off = (tid < 128) ? tid * 4 : 1024 + (tid - 128) * 4;
        *(uint2*)&dr[off] = w;
    }
}

// ---------------------------------------------------------------------------
// Wide branch: one block per row, 16640-elem dot.  wide_w stays L2-hot.
// ---------------------------------------------------------------------------
__global__ __launch_bounds__(256) void k_wide(
    const float* __restrict__ mt, const float* __restrict__ tt,
    const float* __restrict__ cp, const float* __restrict__ ww,
    const float* __restrict__ wb, float* __restrict__ wl)
{
    const int b = blockIdx.x;
    const int tid = threadIdx.x;
    const int wave = tid >> 6, lane = tid & 63;
    float acc = 0.f;
    if (tid < 64) {
        float4 v;
        if (tid < 32) v = ((const float4*)(mt + (size_t)b * Ttag))[tid];
        else          v = ((const float4*)(tt + (size_t)b * Ttag))[tid - 32];
        const float4 w = ((const float4*)ww)[tid];
        acc += dot4(v, w);
    }
    const float4* cp4 = (const float4*)(cp + (size_t)b * (Ttag * Ttag));
    const float4* ww4 = (const float4*)(ww + 2 * Ttag);
#pragma unroll 4
    for (int i = tid; i < (Ttag * Ttag) / 4; i += 256)
        acc += dot4(cp4[i], ww4[i]);
    acc = wave_sum(acc);
    __shared__ float red[4];
    if (lane == 0) red[wave] = acc;
    __syncthreads();
    if (tid == 0) wl[b] = red[0] + red[1] + red[2] + red[3] + wb[0];
}

// ---------------------------------------------------------------------------
// bf16 MFMA GEMM: C[M,N] = act(A[M,K] @ W[N,K]^T + bias), all bf16 in/out,
// fp32 accumulate.  BM=BN=128, BK=64; 4 waves in 2x2, each 64x64.
// LDS padded [128][72] -> conflict-free ds_read_b128 fragment loads.
// ---------------------------------------------------------------------------
__global__ __launch_bounds__(256) void k_gemm_bf16(
    const unsigned short* __restrict__ A, const unsigned short* __restrict__ W,
    const float* __restrict__ bias, unsigned short* __restrict__ C,
    const int K, const int N, const int relu)
{
    __shared__ unsigned short As[128][72];
    __shared__ unsigned short Bs[128][72];
    const int tid = threadIdx.x;
    const int wave = tid >> 6, lane = tid & 63;
    const int wm = wave >> 1, wn = wave & 1;
    const size_t m0 = (size_t)blockIdx.x * 128;
    const size_t n0 = (size_t)blockIdx.y * 128;

    f32x4 acc[4][4];
#pragma unroll
    for (int i = 0; i < 4; ++i)
#pragma unroll
        for (int j = 0; j < 4; ++j) acc[i][j] = (f32x4){0.f, 0.f, 0.f, 0.f};

    uint4 pa[4], pb[4];
    auto loadA = [&](int k0) {
#pragma unroll
        for (int j = 0; j < 4; ++j) {
            const int i = tid + j * 256;
            const int row = i >> 3, c8 = (i & 7) * 8;
            pa[j] = *(const uint4*)(A + (m0 + row) * (size_t)K + k0 + c8);
        }
    };
    auto loadB = [&](int k0) {
#pragma unroll
        for (int j = 0; j < 4; ++j) {
            const int i = tid + j * 256;
            const int row = i >> 3, c8 = (i & 7) * 8;
            pb[j] = *(const uint4*)(W + (n0 + row) * (size_t)K + k0 + c8);
        }
    };

    loadA(0);
    loadB(0);
    for (int k0 = 0; k0 < K; k0 += 64) {
        __syncthreads();
#pragma unroll
        for (int j = 0; j < 4; ++j) {
            const int i = tid + j * 256;
            const int row = i >> 3, c8 = (i & 7) * 8;
            *(uint4*)&As[row][c8] = pa[j];
            *(uint4*)&Bs[row][c8] = pb[j];
        }
        __syncthreads();
        if (k0 + 64 < K) { loadA(k0 + 64); loadB(k0 + 64); }
#pragma unroll
        for (int kk = 0; kk < 2; ++kk) {
            const int krow = kk * 32 + (lane >> 4) * 8;
            bf16x8 af[4], bfr[4];
#pragma unroll
            for (int mm = 0; mm < 4; ++mm)
                af[mm] = *(const bf16x8*)&As[wm * 64 + mm * 16 + (lane & 15)][krow];
#pragma unroll
            for (int nn = 0; nn < 4; ++nn)
                bfr[nn] = *(const bf16x8*)&Bs[wn * 64 + nn * 16 + (lane & 15)][krow];
#pragma unroll
            for (int mm = 0; mm < 4; ++mm)
#pragma unroll
                for (int nn = 0; nn < 4; ++nn)
                    acc[mm][nn] = __builtin_amdgcn_mfma_f32_16x16x32_bf16(
                        af[mm], bfr[nn], acc[mm][nn], 0, 0, 0);
        }
    }

#pragma unroll
    for (int nn = 0; nn < 4; ++nn) {
        const int col = (int)n0 + wn * 64 + nn * 16 + (lane & 15);
        const float bv = bias[col];
#pragma unroll
        for (int mm = 0; mm < 4; ++mm) {
#pragma unroll
            for (int r = 0; r < 4; ++r) {
                const size_t row = m0 + wm * 64 + mm * 16 + (lane >> 4) * 4 + r;
                float v = acc[mm][nn][r] + bv;
                if (relu) v = fmaxf(v, 0.f);
                C[row * N + col] = (unsigned short)f2bf(v);
            }
        }
    }
}

// ---------------------------------------------------------------------------
// Final: deep_out = h3 . d4w + d4b; out = sigmoid(ww*sigmoid(wide)+dw*deep+bias)
// ---------------------------------------------------------------------------
__global__ __launch_bounds__(256) void k_final(
    const unsigned short* __restrict__ h3, const float* __restrict__ d4w,
    const float* __restrict__ d4b, const float* __restrict__ wl,
    const float* __restrict__ wwt, const float* __restrict__ dwt,
    const float* __restrict__ bs, float* __restrict__ out)
{
    const int lane = threadIdx.x & 63;
    const int b = blockIdx.x * 4 + (threadIdx.x >> 6);
    const unsigned short* hr = h3 + (size_t)b * 128;
    float v = bf2f(hr[lane]) * d4w[lane] + bf2f(hr[64 + lane]) * d4w[64 + lane];
    v = wave_sum(v);
    if (lane == 0) {
        const float deep = v + d4b[0];
        const float wo = 1.f / (1.f + __expf(-wl[b]));
        const float z = wwt[0] * wo + dwt[0] * deep + bs[0];
        out[b] = 1.f / (1.f + __expf(-z));
    }
}

extern "C" void kernel_launch(void* const* d_in, const int* in_sizes, int n_in,
                              void* d_out, int out_size, void* d_ws, size_t ws_size,
                              hipStream_t stream)
{
    const float* mt    = (const float*)d_in[0];
    const float* tt    = (const float*)d_in[1];
    const float* cp    = (const float*)d_in[2];
    const float* X     = (const float*)d_in[3];
    const float* cand  = (const float*)d_in[4];
    const float* mdesc = (const float*)d_in[5];
    const int*   clen  = (const int*)d_in[6];
    const float* WK    = (const float*)d_in[7];
    const float* WQ    = (const float*)d_in[8];
    const float* ww    = (const float*)d_in[9];
    const float* wb    = (const float*)d_in[10];
    const float* d1w   = (const float*)d_in[11];
    const float* d1b   = (const float*)d_in[12];
    const float* d2w   = (const float*)d_in[13];
    const float* d2b   = (const float*)d_in[14];
    const float* d3w   = (const float*)d_in[15];
    const float* d3b   = (const float*)d_in[16];
    const float* d4w   = (const float*)d_in[17];
    const float* d4b   = (const float*)d_in[18];
    const float* wwt   = (const float*)d_in[19];
    const float* dwt   = (const float*)d_in[20];
    const float* bs    = (const float*)d_in[21];
    float* out = (float*)d_out;

    // workspace layout (bytes)
    char* w = (char*)d_ws;
    unsigned short* din = (unsigned short*)w;            w += (size_t)Bsz * 1536 * 2;
    float* qt           = (float*)w;                     w += (size_t)Bsz * 512 * 4;
    unsigned short* h1  = (unsigned short*)w;            w += (size_t)Bsz * 512 * 2;
    unsigned short* h2  = (unsigned short*)w;            w += (size_t)Bsz * 256 * 2;
    unsigned short* h3  = (unsigned short*)w;            w += (size_t)Bsz * 128 * 2;
    float* wl           = (float*)w;                     w += (size_t)Bsz * 4;
    unsigned short* w1b = (unsigned short*)w;            w += (size_t)512 * 1536 * 2;
    unsigned short* w2b = (unsigned short*)w;            w += (size_t)256 * 512 * 2;
    unsigned short* w3b = (unsigned short*)w;            w += (size_t)128 * 256 * 2;

    hipLaunchKernelGGL(k_f2bf, dim3(768), dim3(256), 0, stream, d1w, w1b, 512 * 1536 / 4);
    hipLaunchKernelGGL(k_f2bf, dim3(128), dim3(256), 0, stream, d2w, w2b, 256 * 512 / 4);
    hipLaunchKernelGGL(k_f2bf, dim3(32),  dim3(256), 0, stream, d3w, w3b, 128 * 256 / 4);

    hipLaunchKernelGGL(k_qtilde, dim3(256), dim3(256), 0, stream, cand, WQ, WK, qt);
    hipLaunchKernelGGL(k_attn, dim3(Bsz), dim3(256), 0, stream,
                       X, qt, clen, mdesc, cand, din);
    hipLaunchKernelGGL(k_wide, dim3(Bsz), dim3(256), 0, stream,
                       mt, tt, cp, ww, wb, wl);
    hipLaunchKernelGGL(k_gemm_bf16, dim3(64, 4), dim3(256), 0, stream,
                       din, w1b, d1b, h1, 1536, 512, 1);
    hipLaunchKernelGGL(k_gemm_bf16, dim3(64, 2), dim3(256), 0, stream,
                       h1, w2b, d2b, h2, 512, 256, 1);
    hipLaunchKernelGGL(k_gemm_bf16, dim3(64, 1), dim3(256), 0, stream,
                       h2, w3b, d3b, h3, 256, 128, 1);
    hipLaunchKernelGGL(k_final, dim3(Bsz / 4), dim3(256), 0, stream,
                       h3, d4w, d4b, wl, wwt, dwt, bs, out);
}

// Round 3
// 473.876 us; speedup vs baseline: 1.5032x; 1.2578x over previous
//
#include <hip/hip_runtime.h>

#define Bsz 8192
#define Lctx 64
#define Ddim 512
#define DK 64
#define Ttag 128
#define RQT 2   // batch rows per wave in k_qtilde

using f32x4 = __attribute__((ext_vector_type(4))) float;
using bf16x8 = __attribute__((ext_vector_type(8))) short;

__device__ __forceinline__ float wave_sum(float v) {
#pragma unroll
    for (int m = 32; m > 0; m >>= 1) v += __shfl_xor(v, m, 64);
    return v;
}

__device__ __forceinline__ float dot4(float4 a, float4 b) {
    return a.x * b.x + a.y * b.y + a.z * b.z + a.w * b.w;
}

__device__ __forceinline__ unsigned f2bf(float f) {  // RNE, low 16 valid
    unsigned int u = __float_as_uint(f);
    u = u + 0x7fffu + ((u >> 16) & 1u);
    return u >> 16;
}
__device__ __forceinline__ unsigned pack2(float a, float b) {
    return f2bf(a) | (f2bf(b) << 16);
}
__device__ __forceinline__ float bflo(unsigned int v) { return __uint_as_float(v << 16); }
__device__ __forceinline__ float bfhi(unsigned int v) { return __uint_as_float(v & 0xffff0000u); }
__device__ __forceinline__ float bf2f(unsigned short u) { return __uint_as_float((unsigned)u << 16); }

// ---------------------------------------------------------------------------
// fp32 -> bf16 bulk convert (weights).  n4 = element count / 4.
// ---------------------------------------------------------------------------
__global__ __launch_bounds__(256) void k_f2bf(
    const float* __restrict__ s, unsigned short* __restrict__ d, int n4)
{
    const int i = blockIdx.x * 256 + threadIdx.x;
    if (i < n4) {
        const float4 v = ((const float4*)s)[i];
        uint2 w;
        w.x = pack2(v.x, v.y);
        w.y = pack2(v.z, v.w);
        *(uint2*)&d[(size_t)i * 4] = w;
    }
}

// ---------------------------------------------------------------------------
// q̃[b] = W_K^T (W_Q c[b]).  RQT rows per wave; grid Bsz/(RQT*4) blocks so
// 4 blocks/CU stay resident (W_Q/W_K are L2-hot, 128 KB each).
// ---------------------------------------------------------------------------
__global__ __launch_bounds__(256) void k_qtilde(
    const float* __restrict__ C, const float* __restrict__ WQ,
    const float* __restrict__ WK, float* __restrict__ qt)
{
    const int lane = threadIdx.x & 63;
    const int gw = blockIdx.x * 4 + (threadIdx.x >> 6);
    const int b0 = gw * RQT;

    float4 c0[RQT], c1[RQT];
#pragma unroll
    for (int r = 0; r < RQT; ++r) {
        const float4* row = (const float4*)(C + (size_t)(b0 + r) * Ddim);
        c0[r] = row[lane];
        c1[r] = row[64 + lane];
    }
    float tv[RQT];
#pragma unroll
    for (int r = 0; r < RQT; ++r) tv[r] = 0.f;
    for (int k = 0; k < DK; ++k) {
        const float4* wrow = (const float4*)(WQ + (size_t)k * Ddim);
        const float4 w0 = wrow[lane];
        const float4 w1 = wrow[64 + lane];
#pragma unroll
        for (int r = 0; r < RQT; ++r) {
            float p = dot4(c0[r], w0) + dot4(c1[r], w1);
            p = wave_sum(p);
            if (lane == k) tv[r] = p;
        }
    }
    float4 a0[RQT], a1[RQT];
#pragma unroll
    for (int r = 0; r < RQT; ++r) {
        a0[r] = make_float4(0.f, 0.f, 0.f, 0.f);
        a1[r] = make_float4(0.f, 0.f, 0.f, 0.f);
    }
    for (int k = 0; k < DK; ++k) {
        const float4* wrow = (const float4*)(WK + (size_t)k * Ddim);
        const float4 w0 = wrow[lane];
        const float4 w1 = wrow[64 + lane];
#pragma unroll
        for (int r = 0; r < RQT; ++r) {
            const float tk = __shfl(tv[r], k, 64);
            a0[r].x += tk * w0.x; a0[r].y += tk * w0.y;
            a0[r].z += tk * w0.z; a0[r].w += tk * w0.w;
            a1[r].x += tk * w1.x; a1[r].y += tk * w1.y;
            a1[r].z += tk * w1.z; a1[r].w += tk * w1.w;
        }
    }
#pragma unroll
    for (int r = 0; r < RQT; ++r) {
        float4* orow = (float4*)(qt + (size_t)(b0 + r) * Ddim);
        orow[lane] = a0[r];
        orow[64 + lane] = a1[r];
    }
}

// ---------------------------------------------------------------------------
// Ragged attention, register-resident.  launch_bounds(256,2): full VGPR
// budget (no spills), 2 blocks/CU.  Wave w holds rows w*16..w*16+15 packed
// bf16 in 64 VGPRs; loads issued in 4-row (8 KB/wave) bursts; 16 score
// reductions batched into independent butterfly chains.
// ---------------------------------------------------------------------------
__global__ __launch_bounds__(256, 2) void k_attn(
    const float* __restrict__ X, const float* __restrict__ qt,
    const int* __restrict__ clen, const float* __restrict__ mdesc,
    const float* __restrict__ cand, unsigned short* __restrict__ din)
{
    __shared__ float sl[Lctx];
    __shared__ float pl[Lctx];
    __shared__ float part[4][Ddim];   // 8 KB cross-wave partials

    const int b = blockIdx.x;
    const int tid = threadIdx.x;
    const int wave = tid >> 6, lane = tid & 63;

    const float4* qrow = (const float4*)(qt + (size_t)b * Ddim);
    const float4 q0 = qrow[lane];
    const float4 q1 = qrow[64 + lane];
    const float4* xb = (const float4*)(X + (size_t)b * Lctx * Ddim);

    uint2 pk[16][2];   // 16 rows x 8 bf16 per lane
    float sc[16];

#pragma unroll
    for (int g = 0; g < 4; ++g) {
        float4 t0[4], t1[4];
#pragma unroll
        for (int i = 0; i < 4; ++i) {
            const int l = wave * 16 + g * 4 + i;
            t0[i] = xb[l * 128 + lane];
            t1[i] = xb[l * 128 + 64 + lane];
        }
#pragma unroll
        for (int i = 0; i < 4; ++i) {
            const int r = g * 4 + i;
            sc[r] = dot4(t0[i], q0) + dot4(t1[i], q1);
            pk[r][0].x = pack2(t0[i].x, t0[i].y);
            pk[r][0].y = pack2(t0[i].z, t0[i].w);
            pk[r][1].x = pack2(t1[i].x, t1[i].y);
            pk[r][1].y = pack2(t1[i].z, t1[i].w);
        }
    }
    // 16 independent butterfly reductions (96 pipelined shuffles)
#pragma unroll
    for (int r = 0; r < 16; ++r) sc[r] = wave_sum(sc[r]);
    if (lane == 0) {
#pragma unroll
        for (int r = 0; r < 16; ++r) sl[wave * 16 + r] = sc[r];
    }
    __syncthreads();

    const int len = clen[b];
    float m = -1e30f;
    for (int l = 0; l < len; ++l) m = fmaxf(m, sl[l]);
    float denom = 0.f;
    for (int l = 0; l < len; ++l) denom += __expf(sl[l] - m);
    const float rden = 1.f / fmaxf(denom, 1e-30f);
    if (tid < Lctx) pl[tid] = (tid < len) ? __expf(sl[tid] - m) * rden : 0.f;
    __syncthreads();

    float4 a0 = make_float4(0.f, 0.f, 0.f, 0.f);
    float4 a1 = make_float4(0.f, 0.f, 0.f, 0.f);
#pragma unroll
    for (int r = 0; r < 16; ++r) {
        const float p = pl[wave * 16 + r];
        a0.x += p * bflo(pk[r][0].x); a0.y += p * bfhi(pk[r][0].x);
        a0.z += p * bflo(pk[r][0].y); a0.w += p * bfhi(pk[r][0].y);
        a1.x += p * bflo(pk[r][1].x); a1.y += p * bfhi(pk[r][1].x);
        a1.z += p * bflo(pk[r][1].y); a1.w += p * bfhi(pk[r][1].y);
    }
    *(float4*)&part[wave][lane * 4] = a0;
    *(float4*)&part[wave][256 + lane * 4] = a1;
    __syncthreads();

    unsigned short* dr = din + (size_t)b * 1536;
    {
        const int d0 = tid * 2;
        const float2 s0 = *(const float2*)&part[0][d0];
        const float2 s1 = *(const float2*)&part[1][d0];
        const float2 s2 = *(const float2*)&part[2][d0];
        const float2 s3 = *(const float2*)&part[3][d0];
        const float vx = s0.x + s1.x + s2.x + s3.x;
        const float vy = s0.y + s1.y + s2.y + s3.y;
        *(unsigned*)&dr[512 + d0] = pack2(vx, vy);
    }
    {
        const float4 v = (tid < 128)
            ? ((const float4*)(mdesc + (size_t)b * Ddim))[tid]
            : ((const float4*)(cand + (size_t)b * Ddim))[tid - 128];
        uint2 w;
        w.x = pack2(v.x, v.y);
        w.y = pack2(v.z, v.w);
        const int off = (tid < 128) ? tid * 4 : 1024 + (tid - 128) * 4;
        *(uint2*)&dr[off] = w;
    }
}

// ---------------------------------------------------------------------------
// Wide branch: one block per row, 16640-elem dot.  wide_w stays L2-hot.
// ---------------------------------------------------------------------------
__global__ __launch_bounds__(256) void k_wide(
    const float* __restrict__ mt, const float* __restrict__ tt,
    const float* __restrict__ cp, const float* __restrict__ ww,
    const float* __restrict__ wb, float* __restrict__ wl)
{
    const int b = blockIdx.x;
    const int tid = threadIdx.x;
    const int wave = tid >> 6, lane = tid & 63;
    float acc = 0.f;
    if (tid < 64) {
        float4 v;
        if (tid < 32) v = ((const float4*)(mt + (size_t)b * Ttag))[tid];
        else          v = ((const float4*)(tt + (size_t)b * Ttag))[tid - 32];
        const float4 w = ((const float4*)ww)[tid];
        acc += dot4(v, w);
    }
    const float4* cp4 = (const float4*)(cp + (size_t)b * (Ttag * Ttag));
    const float4* ww4 = (const float4*)(ww + 2 * Ttag);
#pragma unroll 4
    for (int i = tid; i < (Ttag * Ttag) / 4; i += 256)
        acc += dot4(cp4[i], ww4[i]);
    acc = wave_sum(acc);
    __shared__ float red[4];
    if (lane == 0) red[wave] = acc;
    __syncthreads();
    if (tid == 0) wl[b] = red[0] + red[1] + red[2] + red[3] + wb[0];
}

// ---------------------------------------------------------------------------
// bf16 MFMA GEMM: C[M,N] = act(A[M,K] @ W[N,K]^T + bias), all bf16 in/out,
// fp32 accumulate.  BM=BN=128, BK=64; 4 waves in 2x2, each 64x64.
// ---------------------------------------------------------------------------
__global__ __launch_bounds__(256) void k_gemm_bf16(
    const unsigned short* __restrict__ A, const unsigned short* __restrict__ W,
    const float* __restrict__ bias, unsigned short* __restrict__ C,
    const int K, const int N, const int relu)
{
    __shared__ unsigned short As[128][72];
    __shared__ unsigned short Bs[128][72];
    const int tid = threadIdx.x;
    const int wave = tid >> 6, lane = tid & 63;
    const int wm = wave >> 1, wn = wave & 1;
    const size_t m0 = (size_t)blockIdx.x * 128;
    const size_t n0 = (size_t)blockIdx.y * 128;

    f32x4 acc[4][4];
#pragma unroll
    for (int i = 0; i < 4; ++i)
#pragma unroll
        for (int j = 0; j < 4; ++j) acc[i][j] = (f32x4){0.f, 0.f, 0.f, 0.f};

    uint4 pa[4], pb[4];
    auto loadA = [&](int k0) {
#pragma unroll
        for (int j = 0; j < 4; ++j) {
            const int i = tid + j * 256;
            const int row = i >> 3, c8 = (i & 7) * 8;
            pa[j] = *(const uint4*)(A + (m0 + row) * (size_t)K + k0 + c8);
        }
    };
    auto loadB = [&](int k0) {
#pragma unroll
        for (int j = 0; j < 4; ++j) {
            const int i = tid + j * 256;
            const int row = i >> 3, c8 = (i & 7) * 8;
            pb[j] = *(const uint4*)(W + (n0 + row) * (size_t)K + k0 + c8);
        }
    };

    loadA(0);
    loadB(0);
    for (int k0 = 0; k0 < K; k0 += 64) {
        __syncthreads();
#pragma unroll
        for (int j = 0; j < 4; ++j) {
            const int i = tid + j * 256;
            const int row = i >> 3, c8 = (i & 7) * 8;
            *(uint4*)&As[row][c8] = pa[j];
            *(uint4*)&Bs[row][c8] = pb[j];
        }
        __syncthreads();
        if (k0 + 64 < K) { loadA(k0 + 64); loadB(k0 + 64); }
#pragma unroll
        for (int kk = 0; kk < 2; ++kk) {
            const int krow = kk * 32 + (lane >> 4) * 8;
            bf16x8 af[4], bfr[4];
#pragma unroll
            for (int mm = 0; mm < 4; ++mm)
                af[mm] = *(const bf16x8*)&As[wm * 64 + mm * 16 + (lane & 15)][krow];
#pragma unroll
            for (int nn = 0; nn < 4; ++nn)
                bfr[nn] = *(const bf16x8*)&Bs[wn * 64 + nn * 16 + (lane & 15)][krow];
#pragma unroll
            for (int mm = 0; mm < 4; ++mm)
#pragma unroll
                for (int nn = 0; nn < 4; ++nn)
                    acc[mm][nn] = __builtin_amdgcn_mfma_f32_16x16x32_bf16(
                        af[mm], bfr[nn], acc[mm][nn], 0, 0, 0);
        }
    }

#pragma unroll
    for (int nn = 0; nn < 4; ++nn) {
        const int col = (int)n0 + wn * 64 + nn * 16 + (lane & 15);
        const float bv = bias[col];
#pragma unroll
        for (int mm = 0; mm < 4; ++mm) {
#pragma unroll
            for (int r = 0; r < 4; ++r) {
                const size_t row = m0 + wm * 64 + mm * 16 + (lane >> 4) * 4 + r;
                float v = acc[mm][nn][r] + bv;
                if (relu) v = fmaxf(v, 0.f);
                C[row * N + col] = (unsigned short)f2bf(v);
            }
        }
    }
}

// ---------------------------------------------------------------------------
// Final: deep_out = h3 . d4w + d4b; out = sigmoid(ww*sigmoid(wide)+dw*deep+bias)
// ---------------------------------------------------------------------------
__global__ __launch_bounds__(256) void k_final(
    const unsigned short* __restrict__ h3, const float* __restrict__ d4w,
    const float* __restrict__ d4b, const float* __restrict__ wl,
    const float* __restrict__ wwt, const float* __restrict__ dwt,
    const float* __restrict__ bs, float* __restrict__ out)
{
    const int lane = threadIdx.x & 63;
    const int b = blockIdx.x * 4 + (threadIdx.x >> 6);
    const unsigned short* hr = h3 + (size_t)b * 128;
    float v = bf2f(hr[lane]) * d4w[lane] + bf2f(hr[64 + lane]) * d4w[64 + lane];
    v = wave_sum(v);
    if (lane == 0) {
        const float deep = v + d4b[0];
        const float wo = 1.f / (1.f + __expf(-wl[b]));
        const float z = wwt[0] * wo + dwt[0] * deep + bs[0];
        out[b] = 1.f / (1.f + __expf(-z));
    }
}

extern "C" void kernel_launch(void* const* d_in, const int* in_sizes, int n_in,
                              void* d_out, int out_size, void* d_ws, size_t ws_size,
                              hipStream_t stream)
{
    const float* mt    = (const float*)d_in[0];
    const float* tt    = (const float*)d_in[1];
    const float* cp    = (const float*)d_in[2];
    const float* X     = (const float*)d_in[3];
    const float* cand  = (const float*)d_in[4];
    const float* mdesc = (const float*)d_in[5];
    const int*   clen  = (const int*)d_in[6];
    const float* WK    = (const float*)d_in[7];
    const float* WQ    = (const float*)d_in[8];
    const float* ww    = (const float*)d_in[9];
    const float* wb    = (const float*)d_in[10];
    const float* d1w   = (const float*)d_in[11];
    const float* d1b   = (const float*)d_in[12];
    const float* d2w   = (const float*)d_in[13];
    const float* d2b   = (const float*)d_in[14];
    const float* d3w   = (const float*)d_in[15];
    const float* d3b   = (const float*)d_in[16];
    const float* d4w   = (const float*)d_in[17];
    const float* d4b   = (const float*)d_in[18];
    const float* wwt   = (const float*)d_in[19];
    const float* dwt   = (const float*)d_in[20];
    const float* bs    = (const float*)d_in[21];
    float* out = (float*)d_out;

    // workspace layout (bytes)
    char* w = (char*)d_ws;
    unsigned short* din = (unsigned short*)w;            w += (size_t)Bsz * 1536 * 2;
    float* qt           = (float*)w;                     w += (size_t)Bsz * 512 * 4;
    unsigned short* h1  = (unsigned short*)w;            w += (size_t)Bsz * 512 * 2;
    unsigned short* h2  = (unsigned short*)w;            w += (size_t)Bsz * 256 * 2;
    unsigned short* h3  = (unsigned short*)w;            w += (size_t)Bsz * 128 * 2;
    float* wl           = (float*)w;                     w += (size_t)Bsz * 4;
    unsigned short* w1b = (unsigned short*)w;            w += (size_t)512 * 1536 * 2;
    unsigned short* w2b = (unsigned short*)w;            w += (size_t)256 * 512 * 2;
    unsigned short* w3b = (unsigned short*)w;            w += (size_t)128 * 256 * 2;

    hipLaunchKernelGGL(k_f2bf, dim3(768), dim3(256), 0, stream, d1w, w1b, 512 * 1536 / 4);
    hipLaunchKernelGGL(k_f2bf, dim3(128), dim3(256), 0, stream, d2w, w2b, 256 * 512 / 4);
    hipLaunchKernelGGL(k_f2bf, dim3(32),  dim3(256), 0, stream, d3w, w3b, 128 * 256 / 4);

    hipLaunchKernelGGL(k_qtilde, dim3(Bsz / (RQT * 4)), dim3(256), 0, stream,
                       cand, WQ, WK, qt);
    hipLaunchKernelGGL(k_attn, dim3(Bsz), dim3(256), 0, stream,
                       X, qt, clen, mdesc, cand, din);
    hipLaunchKernelGGL(k_wide, dim3(Bsz), dim3(256), 0, stream,
                       mt, tt, cp, ww, wb, wl);
    hipLaunchKernelGGL(k_gemm_bf16, dim3(64, 4), dim3(256), 0, stream,
                       din, w1b, d1b, h1, 1536, 512, 1);
    hipLaunchKernelGGL(k_gemm_bf16, dim3(64, 2), dim3(256), 0, stream,
                       h1, w2b, d2b, h2, 512, 256, 1);
    hipLaunchKernelGGL(k_gemm_bf16, dim3(64, 1), dim3(256), 0, stream,
                       h2, w3b, d3b, h3, 256, 128, 1);
    hipLaunchKernelGGL(k_final, dim3(Bsz / 4), dim3(256), 0, stream,
                       h3, d4w, d4b, wl, wwt, dwt, bs, out);
}

// Round 4
// 443.197 us; speedup vs baseline: 1.6072x; 1.0692x over previous
//
#include <hip/hip_runtime.h>

#define Bsz 8192
#define Lctx 64
#define Ddim 512
#define DK 64
#define Ttag 128
#define RQT 2   // batch rows per wave in k_qtilde

using f32x4 = __attribute__((ext_vector_type(4))) float;
using bf16x8 = __attribute__((ext_vector_type(8))) short;

__device__ __forceinline__ float wave_sum(float v) {
#pragma unroll
    for (int m = 32; m > 0; m >>= 1) v += __shfl_xor(v, m, 64);
    return v;
}

__device__ __forceinline__ float dot4(float4 a, float4 b) {
    return a.x * b.x + a.y * b.y + a.z * b.z + a.w * b.w;
}

__device__ __forceinline__ unsigned f2bf(float f) {  // RNE, low 16 valid
    unsigned int u = __float_as_uint(f);
    u = u + 0x7fffu + ((u >> 16) & 1u);
    return u >> 16;
}
__device__ __forceinline__ unsigned pack2(float a, float b) {
    return f2bf(a) | (f2bf(b) << 16);
}
__device__ __forceinline__ float bflo(unsigned int v) { return __uint_as_float(v << 16); }
__device__ __forceinline__ float bfhi(unsigned int v) { return __uint_as_float(v & 0xffff0000u); }
__device__ __forceinline__ float bf2f(unsigned short u) { return __uint_as_float((unsigned)u << 16); }

// ---------------------------------------------------------------------------
// fp32 -> bf16 weight convert, all three MLP weights in one launch.
// Segment sizes in float4 units: 196608 | 32768 | 8192.
// ---------------------------------------------------------------------------
__global__ __launch_bounds__(256) void k_f2bf3(
    const float* __restrict__ s1, unsigned short* __restrict__ d1,
    const float* __restrict__ s2, unsigned short* __restrict__ d2,
    const float* __restrict__ s3, unsigned short* __restrict__ d3)
{
    int i = blockIdx.x * 256 + threadIdx.x;
    const float* s;
    unsigned short* d;
    if (i < 196608)      { s = s1; d = d1; }
    else if (i < 229376) { i -= 196608; s = s2; d = d2; }
    else if (i < 237568) { i -= 229376; s = s3; d = d3; }
    else return;
    const float4 v = ((const float4*)s)[i];
    uint2 w;
    w.x = pack2(v.x, v.y);
    w.y = pack2(v.z, v.w);
    *(uint2*)&d[(size_t)i * 4] = w;
}

// ---------------------------------------------------------------------------
// q̃[b] = W_K^T (W_Q c[b]).  RQT rows per wave, 1024 blocks.
// ---------------------------------------------------------------------------
__global__ __launch_bounds__(256) void k_qtilde(
    const float* __restrict__ C, const float* __restrict__ WQ,
    const float* __restrict__ WK, float* __restrict__ qt)
{
    const int lane = threadIdx.x & 63;
    const int gw = blockIdx.x * 4 + (threadIdx.x >> 6);
    const int b0 = gw * RQT;

    float4 c0[RQT], c1[RQT];
#pragma unroll
    for (int r = 0; r < RQT; ++r) {
        const float4* row = (const float4*)(C + (size_t)(b0 + r) * Ddim);
        c0[r] = row[lane];
        c1[r] = row[64 + lane];
    }
    float tv[RQT];
#pragma unroll
    for (int r = 0; r < RQT; ++r) tv[r] = 0.f;
    for (int k = 0; k < DK; ++k) {
        const float4* wrow = (const float4*)(WQ + (size_t)k * Ddim);
        const float4 w0 = wrow[lane];
        const float4 w1 = wrow[64 + lane];
#pragma unroll
        for (int r = 0; r < RQT; ++r) {
            float p = dot4(c0[r], w0) + dot4(c1[r], w1);
            p = wave_sum(p);
            if (lane == k) tv[r] = p;
        }
    }
    float4 a0[RQT], a1[RQT];
#pragma unroll
    for (int r = 0; r < RQT; ++r) {
        a0[r] = make_float4(0.f, 0.f, 0.f, 0.f);
        a1[r] = make_float4(0.f, 0.f, 0.f, 0.f);
    }
    for (int k = 0; k < DK; ++k) {
        const float4* wrow = (const float4*)(WK + (size_t)k * Ddim);
        const float4 w0 = wrow[lane];
        const float4 w1 = wrow[64 + lane];
#pragma unroll
        for (int r = 0; r < RQT; ++r) {
            const float tk = __shfl(tv[r], k, 64);
            a0[r].x += tk * w0.x; a0[r].y += tk * w0.y;
            a0[r].z += tk * w0.z; a0[r].w += tk * w0.w;
            a1[r].x += tk * w1.x; a1[r].y += tk * w1.y;
            a1[r].z += tk * w1.z; a1[r].w += tk * w1.w;
        }
    }
#pragma unroll
    for (int r = 0; r < RQT; ++r) {
        float4* orow = (float4*)(qt + (size_t)(b0 + r) * Ddim);
        orow[lane] = a0[r];
        orow[64 + lane] = a1[r];
    }
}

// ---------------------------------------------------------------------------
// Fused ragged attention + wide branch, one block per batch row.
// Attention skips rows l >= context_len (probs are zero there) -> expected
// X traffic halves.  Wide's cp stream fills the softmax serialization gaps.
// ---------------------------------------------------------------------------
__global__ __launch_bounds__(256, 2) void k_attn_wide(
    const float* __restrict__ X, const float* __restrict__ qt,
    const int* __restrict__ clen, const float* __restrict__ mdesc,
    const float* __restrict__ cand,
    const float* __restrict__ mt, const float* __restrict__ tt,
    const float* __restrict__ cp, const float* __restrict__ ww,
    const float* __restrict__ wb,
    unsigned short* __restrict__ din, float* __restrict__ wl)
{
    __shared__ float sl[Lctx];
    __shared__ float pl[Lctx];
    __shared__ float part[4][Ddim];   // 8 KB cross-wave partials
    __shared__ float red[4];

    const int b = blockIdx.x;
    const int tid = threadIdx.x;
    const int wave = tid >> 6, lane = tid & 63;
    const int len = clen[b];
    const int nrows = min(16, max(0, len - wave * 16));  // valid rows, this wave

    const float4* qrow = (const float4*)(qt + (size_t)b * Ddim);
    const float4 q0 = qrow[lane];
    const float4 q1 = qrow[64 + lane];
    const float4* xb = (const float4*)(X + (size_t)b * Lctx * Ddim);

    uint2 pk[16][2];   // 16 rows x 8 bf16 per lane
    float sc[16];

    // ---- attention loads + scores, masked rows skipped (wave-uniform) ----
#pragma unroll
    for (int g = 0; g < 4; ++g) {
        if (g * 4 < nrows) {
            float4 t0[4], t1[4];
#pragma unroll
            for (int i = 0; i < 4; ++i) {
                if (g * 4 + i < nrows) {
                    const int l = wave * 16 + g * 4 + i;
                    t0[i] = xb[l * 128 + lane];
                    t1[i] = xb[l * 128 + 64 + lane];
                }
            }
#pragma unroll
            for (int i = 0; i < 4; ++i) {
                if (g * 4 + i < nrows) {
                    const int r = g * 4 + i;
                    sc[r] = dot4(t0[i], q0) + dot4(t1[i], q1);
                    pk[r][0].x = pack2(t0[i].x, t0[i].y);
                    pk[r][0].y = pack2(t0[i].z, t0[i].w);
                    pk[r][1].x = pack2(t1[i].x, t1[i].y);
                    pk[r][1].y = pack2(t1[i].z, t1[i].w);
                }
            }
        }
    }
#pragma unroll
    for (int r = 0; r < 16; ++r)
        if (r < nrows) sc[r] = wave_sum(sc[r]);
    if (lane == 0) {
#pragma unroll
        for (int r = 0; r < 16; ++r)
            if (r < nrows) sl[wave * 16 + r] = sc[r];
    }

    // ---- wide branch stream (fills the gap before the barrier) ----
    float wacc = 0.f;
    if (tid < 64) {
        float4 v;
        if (tid < 32) v = ((const float4*)(mt + (size_t)b * Ttag))[tid];
        else          v = ((const float4*)(tt + (size_t)b * Ttag))[tid - 32];
        wacc += dot4(v, ((const float4*)ww)[tid]);
    }
    {
        const float4* cp4 = (const float4*)(cp + (size_t)b * (Ttag * Ttag));
        const float4* ww4 = (const float4*)(ww + 2 * Ttag);
#pragma unroll 4
        for (int i = tid; i < (Ttag * Ttag) / 4; i += 256)
            wacc += dot4(cp4[i], ww4[i]);
    }
    wacc = wave_sum(wacc);
    if (lane == 0) red[wave] = wacc;

    __syncthreads();

    // ---- masked softmax ----
    float m = -1e30f;
    for (int l = 0; l < len; ++l) m = fmaxf(m, sl[l]);
    float denom = 0.f;
    for (int l = 0; l < len; ++l) denom += __expf(sl[l] - m);
    const float rden = 1.f / fmaxf(denom, 1e-30f);
    if (tid < Lctx) pl[tid] = (tid < len) ? __expf(sl[tid] - m) * rden : 0.f;
    __syncthreads();

    // ---- weighted sum from registers ----
    float4 a0 = make_float4(0.f, 0.f, 0.f, 0.f);
    float4 a1 = make_float4(0.f, 0.f, 0.f, 0.f);
#pragma unroll
    for (int r = 0; r < 16; ++r) {
        if (r < nrows) {
            const float p = pl[wave * 16 + r];
            a0.x += p * bflo(pk[r][0].x); a0.y += p * bfhi(pk[r][0].x);
            a0.z += p * bflo(pk[r][0].y); a0.w += p * bfhi(pk[r][0].y);
            a1.x += p * bflo(pk[r][1].x); a1.y += p * bfhi(pk[r][1].x);
            a1.z += p * bflo(pk[r][1].y); a1.w += p * bfhi(pk[r][1].y);
        }
    }
    *(float4*)&part[wave][lane * 4] = a0;
    *(float4*)&part[wave][256 + lane * 4] = a1;
    __syncthreads();

    unsigned short* dr = din + (size_t)b * 1536;
    {
        const int d0 = tid * 2;
        const float2 s0 = *(const float2*)&part[0][d0];
        const float2 s1 = *(const float2*)&part[1][d0];
        const float2 s2 = *(const float2*)&part[2][d0];
        const float2 s3 = *(const float2*)&part[3][d0];
        const float vx = s0.x + s1.x + s2.x + s3.x;
        const float vy = s0.y + s1.y + s2.y + s3.y;
        *(unsigned*)&dr[512 + d0] = pack2(vx, vy);
    }
    {
        const float4 v = (tid < 128)
            ? ((const float4*)(mdesc + (size_t)b * Ddim))[tid]
            : ((const float4*)(cand + (size_t)b * Ddim))[tid - 128];
        uint2 w;
        w.x = pack2(v.x, v.y);
        w.y = pack2(v.z, v.w);
        const int off = (tid < 128) ? tid * 4 : 1024 + (tid - 128) * 4;
        *(uint2*)&dr[off] = w;
    }
    if (tid == 0) wl[b] = red[0] + red[1] + red[2] + red[3] + wb[0];
}

// ---------------------------------------------------------------------------
// bf16 MFMA GEMM: C[M,N] = act(A[M,K] @ W[N,K]^T + bias), all bf16 in/out,
// fp32 accumulate.  BM=BN=128, BK=64; 4 waves in 2x2, each 64x64.
// ---------------------------------------------------------------------------
__global__ __launch_bounds__(256) void k_gemm_bf16(
    const unsigned short* __restrict__ A, const unsigned short* __restrict__ W,
    const float* __restrict__ bias, unsigned short* __restrict__ C,
    const int K, const int N, const int relu)
{
    __shared__ unsigned short As[128][72];
    __shared__ unsigned short Bs[128][72];
    const int tid = threadIdx.x;
    const int wave = tid >> 6, lane = tid & 63;
    const int wm = wave >> 1, wn = wave & 1;
    const size_t m0 = (size_t)blockIdx.x * 128;
    const size_t n0 = (size_t)blockIdx.y * 128;

    f32x4 acc[4][4];
#pragma unroll
    for (int i = 0; i < 4; ++i)
#pragma unroll
        for (int j = 0; j < 4; ++j) acc[i][j] = (f32x4){0.f, 0.f, 0.f, 0.f};

    uint4 pa[4], pb[4];
    auto loadA = [&](int k0) {
#pragma unroll
        for (int j = 0; j < 4; ++j) {
            const int i = tid + j * 256;
            const int row = i >> 3, c8 = (i & 7) * 8;
            pa[j] = *(const uint4*)(A + (m0 + row) * (size_t)K + k0 + c8);
        }
    };
    auto loadB = [&](int k0) {
#pragma unroll
        for (int j = 0; j < 4; ++j) {
            const int i = tid + j * 256;
            const int row = i >> 3, c8 = (i & 7) * 8;
            pb[j] = *(const uint4*)(W + (n0 + row) * (size_t)K + k0 + c8);
        }
    };

    loadA(0);
    loadB(0);
    for (int k0 = 0; k0 < K; k0 += 64) {
        __syncthreads();
#pragma unroll
        for (int j = 0; j < 4; ++j) {
            const int i = tid + j * 256;
            const int row = i >> 3, c8 = (i & 7) * 8;
            *(uint4*)&As[row][c8] = pa[j];
            *(uint4*)&Bs[row][c8] = pb[j];
        }
        __syncthreads();
        if (k0 + 64 < K) { loadA(k0 + 64); loadB(k0 + 64); }
#pragma unroll
        for (int kk = 0; kk < 2; ++kk) {
            const int krow = kk * 32 + (lane >> 4) * 8;
            bf16x8 af[4], bfr[4];
#pragma unroll
            for (int mm = 0; mm < 4; ++mm)
                af[mm] = *(const bf16x8*)&As[wm * 64 + mm * 16 + (lane & 15)][krow];
#pragma unroll
            for (int nn = 0; nn < 4; ++nn)
                bfr[nn] = *(const bf16x8*)&Bs[wn * 64 + nn * 16 + (lane & 15)][krow];
#pragma unroll
            for (int mm = 0; mm < 4; ++mm)
#pragma unroll
                for (int nn = 0; nn < 4; ++nn)
                    acc[mm][nn] = __builtin_amdgcn_mfma_f32_16x16x32_bf16(
                        af[mm], bfr[nn], acc[mm][nn], 0, 0, 0);
        }
    }

#pragma unroll
    for (int nn = 0; nn < 4; ++nn) {
        const int col = (int)n0 + wn * 64 + nn * 16 + (lane & 15);
        const float bv = bias[col];
#pragma unroll
        for (int mm = 0; mm < 4; ++mm) {
#pragma unroll
            for (int r = 0; r < 4; ++r) {
                const size_t row = m0 + wm * 64 + mm * 16 + (lane >> 4) * 4 + r;
                float v = acc[mm][nn][r] + bv;
                if (relu) v = fmaxf(v, 0.f);
                C[row * N + col] = (unsigned short)f2bf(v);
            }
        }
    }
}

// ---------------------------------------------------------------------------
// Final: deep_out = h3 . d4w + d4b; out = sigmoid(ww*sigmoid(wide)+dw*deep+bias)
// ---------------------------------------------------------------------------
__global__ __launch_bounds__(256) void k_final(
    const unsigned short* __restrict__ h3, const float* __restrict__ d4w,
    const float* __restrict__ d4b, const float* __restrict__ wl,
    const float* __restrict__ wwt, const float* __restrict__ dwt,
    const float* __restrict__ bs, float* __restrict__ out)
{
    const int lane = threadIdx.x & 63;
    const int b = blockIdx.x * 4 + (threadIdx.x >> 6);
    const unsigned short* hr = h3 + (size_t)b * 128;
    float v = bf2f(hr[lane]) * d4w[lane] + bf2f(hr[64 + lane]) * d4w[64 + lane];
    v = wave_sum(v);
    if (lane == 0) {
        const float deep = v + d4b[0];
        const float wo = 1.f / (1.f + __expf(-wl[b]));
        const float z = wwt[0] * wo + dwt[0] * deep + bs[0];
        out[b] = 1.f / (1.f + __expf(-z));
    }
}

extern "C" void kernel_launch(void* const* d_in, const int* in_sizes, int n_in,
                              void* d_out, int out_size, void* d_ws, size_t ws_size,
                              hipStream_t stream)
{
    const float* mt    = (const float*)d_in[0];
    const float* tt    = (const float*)d_in[1];
    const float* cp    = (const float*)d_in[2];
    const float* X     = (const float*)d_in[3];
    const float* cand  = (const float*)d_in[4];
    const float* mdesc = (const float*)d_in[5];
    const int*   clen  = (const int*)d_in[6];
    const float* WK    = (const float*)d_in[7];
    const float* WQ    = (const float*)d_in[8];
    const float* ww    = (const float*)d_in[9];
    const float* wb    = (const float*)d_in[10];
    const float* d1w   = (const float*)d_in[11];
    const float* d1b   = (const float*)d_in[12];
    const float* d2w   = (const float*)d_in[13];
    const float* d2b   = (const float*)d_in[14];
    const float* d3w   = (const float*)d_in[15];
    const float* d3b   = (const float*)d_in[16];
    const float* d4w   = (const float*)d_in[17];
    const float* d4b   = (const float*)d_in[18];
    const float* wwt   = (const float*)d_in[19];
    const float* dwt   = (const float*)d_in[20];
    const float* bs    = (const float*)d_in[21];
    float* out = (float*)d_out;

    // workspace layout (bytes)
    char* w = (char*)d_ws;
    unsigned short* din = (unsigned short*)w;            w += (size_t)Bsz * 1536 * 2;
    float* qt           = (float*)w;                     w += (size_t)Bsz * 512 * 4;
    unsigned short* h1  = (unsigned short*)w;            w += (size_t)Bsz * 512 * 2;
    unsigned short* h2  = (unsigned short*)w;            w += (size_t)Bsz * 256 * 2;
    unsigned short* h3  = (unsigned short*)w;            w += (size_t)Bsz * 128 * 2;
    float* wl           = (float*)w;                     w += (size_t)Bsz * 4;
    unsigned short* w1b = (unsigned short*)w;            w += (size_t)512 * 1536 * 2;
    unsigned short* w2b = (unsigned short*)w;            w += (size_t)256 * 512 * 2;
    unsigned short* w3b = (unsigned short*)w;            w += (size_t)128 * 256 * 2;

    hipLaunchKernelGGL(k_f2bf3, dim3(928), dim3(256), 0, stream,
                       d1w, w1b, d2w, w2b, d3w, w3b);
    hipLaunchKernelGGL(k_qtilde, dim3(Bsz / (RQT * 4)), dim3(256), 0, stream,
                       cand, WQ, WK, qt);
    hipLaunchKernelGGL(k_attn_wide, dim3(Bsz), dim3(256), 0, stream,
                       X, qt, clen, mdesc, cand, mt, tt, cp, ww, wb, din, wl);
    hipLaunchKernelGGL(k_gemm_bf16, dim3(64, 4), dim3(256), 0, stream,
                       din, w1b, d1b, h1, 1536, 512, 1);
    hipLaunchKernelGGL(k_gemm_bf16, dim3(64, 2), dim3(256), 0, stream,
                       h1, w2b, d2b, h2, 512, 256, 1);
    hipLaunchKernelGGL(k_gemm_bf16, dim3(64, 1), dim3(256), 0, stream,
                       h2, w3b, d3b, h3, 256, 128, 1);
    hipLaunchKernelGGL(k_final, dim3(Bsz / 4), dim3(256), 0, stream,
                       h3, d4w, d4b, wl, wwt, dwt, bs, out);
}

// Round 5
// 407.139 us; speedup vs baseline: 1.7495x; 1.0886x over previous
//
#include <hip/hip_runtime.h>

#define Bsz 8192
#define Lctx 64
#define Ddim 512
#define DK 64
#define Ttag 128
#define RQT 2   // batch rows per wave in k_qtilde

using f32x4 = __attribute__((ext_vector_type(4))) float;
using bf16x8 = __attribute__((ext_vector_type(8))) short;

__device__ __forceinline__ float wave_sum(float v) {
#pragma unroll
    for (int m = 32; m > 0; m >>= 1) v += __shfl_xor(v, m, 64);
    return v;
}

__device__ __forceinline__ float dot4(float4 a, float4 b) {
    return a.x * b.x + a.y * b.y + a.z * b.z + a.w * b.w;
}

__device__ __forceinline__ unsigned f2bf(float f) {  // RNE, low 16 valid
    unsigned int u = __float_as_uint(f);
    u = u + 0x7fffu + ((u >> 16) & 1u);
    return u >> 16;
}
__device__ __forceinline__ unsigned pack2(float a, float b) {
    return f2bf(a) | (f2bf(b) << 16);
}
__device__ __forceinline__ float bflo(unsigned int v) { return __uint_as_float(v << 16); }
__device__ __forceinline__ float bfhi(unsigned int v) { return __uint_as_float(v & 0xffff0000u); }
__device__ __forceinline__ float bf2f(unsigned short u) { return __uint_as_float((unsigned)u << 16); }

// ---------------------------------------------------------------------------
// fp32 -> bf16 weight convert, all three MLP weights in one launch.
// Segment sizes in float4 units: 196608 | 32768 | 8192.
// ---------------------------------------------------------------------------
__global__ __launch_bounds__(256) void k_f2bf3(
    const float* __restrict__ s1, unsigned short* __restrict__ d1,
    const float* __restrict__ s2, unsigned short* __restrict__ d2,
    const float* __restrict__ s3, unsigned short* __restrict__ d3)
{
    int i = blockIdx.x * 256 + threadIdx.x;
    const float* s;
    unsigned short* d;
    if (i < 196608)      { s = s1; d = d1; }
    else if (i < 229376) { i -= 196608; s = s2; d = d2; }
    else if (i < 237568) { i -= 229376; s = s3; d = d3; }
    else return;
    const float4 v = ((const float4*)s)[i];
    uint2 w;
    w.x = pack2(v.x, v.y);
    w.y = pack2(v.z, v.w);
    *(uint2*)&d[(size_t)i * 4] = w;
}

// ---------------------------------------------------------------------------
// q̃[b] = W_K^T (W_Q c[b]).  RQT rows per wave, 1024 blocks.
// ---------------------------------------------------------------------------
__global__ __launch_bounds__(256) void k_qtilde(
    const float* __restrict__ C, const float* __restrict__ WQ,
    const float* __restrict__ WK, float* __restrict__ qt)
{
    const int lane = threadIdx.x & 63;
    const int gw = blockIdx.x * 4 + (threadIdx.x >> 6);
    const int b0 = gw * RQT;

    float4 c0[RQT], c1[RQT];
#pragma unroll
    for (int r = 0; r < RQT; ++r) {
        const float4* row = (const float4*)(C + (size_t)(b0 + r) * Ddim);
        c0[r] = row[lane];
        c1[r] = row[64 + lane];
    }
    float tv[RQT];
#pragma unroll
    for (int r = 0; r < RQT; ++r) tv[r] = 0.f;
    for (int k = 0; k < DK; ++k) {
        const float4* wrow = (const float4*)(WQ + (size_t)k * Ddim);
        const float4 w0 = wrow[lane];
        const float4 w1 = wrow[64 + lane];
#pragma unroll
        for (int r = 0; r < RQT; ++r) {
            float p = dot4(c0[r], w0) + dot4(c1[r], w1);
            p = wave_sum(p);
            if (lane == k) tv[r] = p;
        }
    }
    float4 a0[RQT], a1[RQT];
#pragma unroll
    for (int r = 0; r < RQT; ++r) {
        a0[r] = make_float4(0.f, 0.f, 0.f, 0.f);
        a1[r] = make_float4(0.f, 0.f, 0.f, 0.f);
    }
    for (int k = 0; k < DK; ++k) {
        const float4* wrow = (const float4*)(WK + (size_t)k * Ddim);
        const float4 w0 = wrow[lane];
        const float4 w1 = wrow[64 + lane];
#pragma unroll
        for (int r = 0; r < RQT; ++r) {
            const float tk = __shfl(tv[r], k, 64);
            a0[r].x += tk * w0.x; a0[r].y += tk * w0.y;
            a0[r].z += tk * w0.z; a0[r].w += tk * w0.w;
            a1[r].x += tk * w1.x; a1[r].y += tk * w1.y;
            a1[r].z += tk * w1.z; a1[r].w += tk * w1.w;
        }
    }
#pragma unroll
    for (int r = 0; r < RQT; ++r) {
        float4* orow = (float4*)(qt + (size_t)(b0 + r) * Ddim);
        orow[lane] = a0[r];
        orow[64 + lane] = a1[r];
    }
}

// ---------------------------------------------------------------------------
// Fused ragged attention + wide branch, one 512-thread block per batch row.
// 8 waves x 8 rows/wave; full-wave load burst (16 dwordx4 in flight) with
// clamped row indices so masked waves still pipeline; 4 waves/SIMD for TLP.
// ---------------------------------------------------------------------------
__global__ __launch_bounds__(512, 2) void k_attn_wide(
    const float* __restrict__ X, const float* __restrict__ qt,
    const int* __restrict__ clen, const float* __restrict__ mdesc,
    const float* __restrict__ cand,
    const float* __restrict__ mt, const float* __restrict__ tt,
    const float* __restrict__ cp, const float* __restrict__ ww,
    const float* __restrict__ wb,
    unsigned short* __restrict__ din, float* __restrict__ wl)
{
    __shared__ float sl[Lctx];
    __shared__ float pl[Lctx];
    __shared__ float part[8][Ddim];   // 16 KB cross-wave partials
    __shared__ float red[8];

    const int b = blockIdx.x;
    const int tid = threadIdx.x;
    const int wave = tid >> 6, lane = tid & 63;
    const int len = clen[b];
    const int nrows = min(8, max(0, len - wave * 8));  // valid rows, this wave

    const float4* qrow = (const float4*)(qt + (size_t)b * Ddim);
    const float4 q0 = qrow[lane];
    const float4 q1 = qrow[64 + lane];
    const float4* xb = (const float4*)(X + (size_t)b * Lctx * Ddim);

    uint2 pk[8][2];   // 8 rows x 8 bf16 per lane
    float sc[8];

    // ---- attention: one full-wave burst (16 loads in flight), then score ----
    if (nrows > 0) {
        float4 t0[8], t1[8];
#pragma unroll
        for (int r = 0; r < 8; ++r) {
            const int l = wave * 8 + min(r, nrows - 1);  // clamp: L1-hit re-read
            t0[r] = xb[l * 128 + lane];
            t1[r] = xb[l * 128 + 64 + lane];
        }
#pragma unroll
        for (int r = 0; r < 8; ++r) {
            if (r < nrows) {
                sc[r] = dot4(t0[r], q0) + dot4(t1[r], q1);
                pk[r][0].x = pack2(t0[r].x, t0[r].y);
                pk[r][0].y = pack2(t0[r].z, t0[r].w);
                pk[r][1].x = pack2(t1[r].x, t1[r].y);
                pk[r][1].y = pack2(t1[r].z, t1[r].w);
            }
        }
#pragma unroll
        for (int r = 0; r < 8; ++r)
            if (r < nrows) sc[r] = wave_sum(sc[r]);
        if (lane == 0) {
#pragma unroll
            for (int r = 0; r < 8; ++r)
                if (r < nrows) sl[wave * 8 + r] = sc[r];
        }
    }

    // ---- wide branch stream (fills latency before the barrier) ----
    float wacc = 0.f;
    if (tid < 64) {
        float4 v;
        if (tid < 32) v = ((const float4*)(mt + (size_t)b * Ttag))[tid];
        else          v = ((const float4*)(tt + (size_t)b * Ttag))[tid - 32];
        wacc += dot4(v, ((const float4*)ww)[tid]);
    }
    {
        const float4* cp4 = (const float4*)(cp + (size_t)b * (Ttag * Ttag));
        const float4* ww4 = (const float4*)(ww + 2 * Ttag);
#pragma unroll 4
        for (int i = tid; i < (Ttag * Ttag) / 4; i += 512)
            wacc += dot4(cp4[i], ww4[i]);
    }
    wacc = wave_sum(wacc);
    if (lane == 0) red[wave] = wacc;

    __syncthreads();

    // ---- masked softmax, wave-parallel on wave 0 ----
    if (wave == 0) {
        const float s = (lane < len) ? sl[lane] : -1e30f;
        float m = s;
#pragma unroll
        for (int msk = 32; msk > 0; msk >>= 1)
            m = fmaxf(m, __shfl_xor(m, msk, 64));
        const float e = (lane < len) ? __expf(s - m) : 0.f;
        const float d = wave_sum(e);
        pl[lane] = e * (1.f / fmaxf(d, 1e-30f));
    }
    __syncthreads();

    // ---- weighted sum from registers ----
    float4 a0 = make_float4(0.f, 0.f, 0.f, 0.f);
    float4 a1 = make_float4(0.f, 0.f, 0.f, 0.f);
#pragma unroll
    for (int r = 0; r < 8; ++r) {
        if (r < nrows) {
            const float p = pl[wave * 8 + r];
            a0.x += p * bflo(pk[r][0].x); a0.y += p * bfhi(pk[r][0].x);
            a0.z += p * bflo(pk[r][0].y); a0.w += p * bfhi(pk[r][0].y);
            a1.x += p * bflo(pk[r][1].x); a1.y += p * bfhi(pk[r][1].x);
            a1.z += p * bflo(pk[r][1].y); a1.w += p * bfhi(pk[r][1].y);
        }
    }
    *(float4*)&part[wave][lane * 4] = a0;
    *(float4*)&part[wave][256 + lane * 4] = a1;
    __syncthreads();

    unsigned short* dr = din + (size_t)b * 1536;
    {
        float v = 0.f;
#pragma unroll
        for (int w8 = 0; w8 < 8; ++w8) v += part[w8][tid];
        dr[512 + tid] = (unsigned short)f2bf(v);
    }
    if (tid < 256) {
        const float4 v = (tid < 128)
            ? ((const float4*)(mdesc + (size_t)b * Ddim))[tid]
            : ((const float4*)(cand + (size_t)b * Ddim))[tid - 128];
        uint2 w;
        w.x = pack2(v.x, v.y);
        w.y = pack2(v.z, v.w);
        const int off = (tid < 128) ? tid * 4 : 1024 + (tid - 128) * 4;
        *(uint2*)&dr[off] = w;
    }
    if (tid == 0)
        wl[b] = red[0] + red[1] + red[2] + red[3] +
                red[4] + red[5] + red[6] + red[7] + wb[0];
}

// ---------------------------------------------------------------------------
// bf16 MFMA GEMM: C[M,N] = act(A[M,K] @ W[N,K]^T + bias), all bf16 in/out,
// fp32 accumulate.  BM=BN=128, BK=64; 4 waves in 2x2, each 64x64.
// ---------------------------------------------------------------------------
__global__ __launch_bounds__(256) void k_gemm_bf16(
    const unsigned short* __restrict__ A, const unsigned short* __restrict__ W,
    const float* __restrict__ bias, unsigned short* __restrict__ C,
    const int K, const int N, const int relu)
{
    __shared__ unsigned short As[128][72];
    __shared__ unsigned short Bs[128][72];
    const int tid = threadIdx.x;
    const int wave = tid >> 6, lane = tid & 63;
    const int wm = wave >> 1, wn = wave & 1;
    const size_t m0 = (size_t)blockIdx.x * 128;
    const size_t n0 = (size_t)blockIdx.y * 128;

    f32x4 acc[4][4];
#pragma unroll
    for (int i = 0; i < 4; ++i)
#pragma unroll
        for (int j = 0; j < 4; ++j) acc[i][j] = (f32x4){0.f, 0.f, 0.f, 0.f};

    uint4 pa[4], pb[4];
    auto loadA = [&](int k0) {
#pragma unroll
        for (int j = 0; j < 4; ++j) {
            const int i = tid + j * 256;
            const int row = i >> 3, c8 = (i & 7) * 8;
            pa[j] = *(const uint4*)(A + (m0 + row) * (size_t)K + k0 + c8);
        }
    };
    auto loadB = [&](int k0) {
#pragma unroll
        for (int j = 0; j < 4; ++j) {
            const int i = tid + j * 256;
            const int row = i >> 3, c8 = (i & 7) * 8;
            pb[j] = *(const uint4*)(W + (n0 + row) * (size_t)K + k0 + c8);
        }
    };

    loadA(0);
    loadB(0);
    for (int k0 = 0; k0 < K; k0 += 64) {
        __syncthreads();
#pragma unroll
        for (int j = 0; j < 4; ++j) {
            const int i = tid + j * 256;
            const int row = i >> 3, c8 = (i & 7) * 8;
            *(uint4*)&As[row][c8] = pa[j];
            *(uint4*)&Bs[row][c8] = pb[j];
        }
        __syncthreads();
        if (k0 + 64 < K) { loadA(k0 + 64); loadB(k0 + 64); }
#pragma unroll
        for (int kk = 0; kk < 2; ++kk) {
            const int krow = kk * 32 + (lane >> 4) * 8;
            bf16x8 af[4], bfr[4];
#pragma unroll
            for (int mm = 0; mm < 4; ++mm)
                af[mm] = *(const bf16x8*)&As[wm * 64 + mm * 16 + (lane & 15)][krow];
#pragma unroll
            for (int nn = 0; nn < 4; ++nn)
                bfr[nn] = *(const bf16x8*)&Bs[wn * 64 + nn * 16 + (lane & 15)][krow];
#pragma unroll
            for (int mm = 0; mm < 4; ++mm)
#pragma unroll
                for (int nn = 0; nn < 4; ++nn)
                    acc[mm][nn] = __builtin_amdgcn_mfma_f32_16x16x32_bf16(
                        af[mm], bfr[nn], acc[mm][nn], 0, 0, 0);
        }
    }

#pragma unroll
    for (int nn = 0; nn < 4; ++nn) {
        const int col = (int)n0 + wn * 64 + nn * 16 + (lane & 15);
        const float bv = bias[col];
#pragma unroll
        for (int mm = 0; mm < 4; ++mm) {
#pragma unroll
            for (int r = 0; r < 4; ++r) {
                const size_t row = m0 + wm * 64 + mm * 16 + (lane >> 4) * 4 + r;
                float v = acc[mm][nn][r] + bv;
                if (relu) v = fmaxf(v, 0.f);
                C[row * N + col] = (unsigned short)f2bf(v);
            }
        }
    }
}

// ---------------------------------------------------------------------------
// Final: deep_out = h3 . d4w + d4b; out = sigmoid(ww*sigmoid(wide)+dw*deep+bias)
// ---------------------------------------------------------------------------
__global__ __launch_bounds__(256) void k_final(
    const unsigned short* __restrict__ h3, const float* __restrict__ d4w,
    const float* __restrict__ d4b, const float* __restrict__ wl,
    const float* __restrict__ wwt, const float* __restrict__ dwt,
    const float* __restrict__ bs, float* __restrict__ out)
{
    const int lane = threadIdx.x & 63;
    const int b = blockIdx.x * 4 + (threadIdx.x >> 6);
    const unsigned short* hr = h3 + (size_t)b * 128;
    float v = bf2f(hr[lane]) * d4w[lane] + bf2f(hr[64 + lane]) * d4w[64 + lane];
    v = wave_sum(v);
    if (lane == 0) {
        const float deep = v + d4b[0];
        const float wo = 1.f / (1.f + __expf(-wl[b]));
        const float z = wwt[0] * wo + dwt[0] * deep + bs[0];
        out[b] = 1.f / (1.f + __expf(-z));
    }
}

extern "C" void kernel_launch(void* const* d_in, const int* in_sizes, int n_in,
                              void* d_out, int out_size, void* d_ws, size_t ws_size,
                              hipStream_t stream)
{
    const float* mt    = (const float*)d_in[0];
    const float* tt    = (const float*)d_in[1];
    const float* cp    = (const float*)d_in[2];
    const float* X     = (const float*)d_in[3];
    const float* cand  = (const float*)d_in[4];
    const float* mdesc = (const float*)d_in[5];
    const int*   clen  = (const int*)d_in[6];
    const float* WK    = (const float*)d_in[7];
    const float* WQ    = (const float*)d_in[8];
    const float* ww    = (const float*)d_in[9];
    const float* wb    = (const float*)d_in[10];
    const float* d1w   = (const float*)d_in[11];
    const float* d1b   = (const float*)d_in[12];
    const float* d2w   = (const float*)d_in[13];
    const float* d2b   = (const float*)d_in[14];
    const float* d3w   = (const float*)d_in[15];
    const float* d3b   = (const float*)d_in[16];
    const float* d4w   = (const float*)d_in[17];
    const float* d4b   = (const float*)d_in[18];
    const float* wwt   = (const float*)d_in[19];
    const float* dwt   = (const float*)d_in[20];
    const float* bs    = (const float*)d_in[21];
    float* out = (float*)d_out;

    // workspace layout (bytes)
    char* w = (char*)d_ws;
    unsigned short* din = (unsigned short*)w;            w += (size_t)Bsz * 1536 * 2;
    float* qt           = (float*)w;                     w += (size_t)Bsz * 512 * 4;
    unsigned short* h1  = (unsigned short*)w;            w += (size_t)Bsz * 512 * 2;
    unsigned short* h2  = (unsigned short*)w;            w += (size_t)Bsz * 256 * 2;
    unsigned short* h3  = (unsigned short*)w;            w += (size_t)Bsz * 128 * 2;
    float* wl           = (float*)w;                     w += (size_t)Bsz * 4;
    unsigned short* w1b = (unsigned short*)w;            w += (size_t)512 * 1536 * 2;
    unsigned short* w2b = (unsigned short*)w;            w += (size_t)256 * 512 * 2;
    unsigned short* w3b = (unsigned short*)w;            w += (size_t)128 * 256 * 2;

    hipLaunchKernelGGL(k_f2bf3, dim3(928), dim3(256), 0, stream,
                       d1w, w1b, d2w, w2b, d3w, w3b);
    hipLaunchKernelGGL(k_qtilde, dim3(Bsz / (RQT * 4)), dim3(256), 0, stream,
                       cand, WQ, WK, qt);
    hipLaunchKernelGGL(k_attn_wide, dim3(Bsz), dim3(512), 0, stream,
                       X, qt, clen, mdesc, cand, mt, tt, cp, ww, wb, din, wl);
    hipLaunchKernelGGL(k_gemm_bf16, dim3(64, 4), dim3(256), 0, stream,
                       din, w1b, d1b, h1, 1536, 512, 1);
    hipLaunchKernelGGL(k_gemm_bf16, dim3(64, 2), dim3(256), 0, stream,
                       h1, w2b, d2b, h2, 512, 256, 1);
    hipLaunchKernelGGL(k_gemm_bf16, dim3(64, 1), dim3(256), 0, stream,
                       h2, w3b, d3b, h3, 256, 128, 1);
    hipLaunchKernelGGL(k_final, dim3(Bsz / 4), dim3(256), 0, stream,
                       h3, d4w, d4b, wl, wwt, dwt, bs, out);
}